// Round 1
// baseline (356.966 us; speedup 1.0000x reference)
//
#include <hip/hip_runtime.h>
#include <cstdint>
#include <cmath>

typedef short s16x8 __attribute__((ext_vector_type(8)));
typedef float f32x4 __attribute__((ext_vector_type(4)));

#define AS_G __attribute__((address_space(1)))
#define AS_L __attribute__((address_space(3)))

__device__ __forceinline__ void ld16_to_lds(const void* g, const void* l) {
    __builtin_amdgcn_global_load_lds((AS_G void*)(g), (AS_L void*)(l), 16, 0, 0);
}

__device__ __forceinline__ short f2bf(float f) {
    union { float f; uint32_t u; } v; v.f = f;
    uint32_t r = v.u + 0x7fffu + ((v.u >> 16) & 1u);
    return (short)(r >> 16);
}

// ---------------------------------------------------------------------------
// C[M,N] = A[M,K] @ Bt[N,K]^T + bias[N]; A,Bt bf16 (as short), out f32 or bf16
// Tile: BM=128, BN=64, BK=32. 256 threads = 4 waves, wave = 64 rows x 32 cols.
// LDS kc-major chunk layout (chunk c = kc*ROWS + row at &buf[c*8]) so that
// global_load_lds's lane-contiguous LDS writes match, and ds_read_b128
// fragment reads are bank-conflict-free (<=2-way).
// ---------------------------------------------------------------------------
template<int F32OUT>
__global__ __launch_bounds__(256)
void gemm_bt(const short* __restrict__ A, const short* __restrict__ Bt,
             const float* __restrict__ bias, void* __restrict__ Cv,
             const int M, const int N, const int K)
{
    __shared__ short As[4 * 128 * 8];  // 8 KB: chunk c = kc*128 + row
    __shared__ short Bs[4 * 64 * 8];   // 4 KB: chunk c = kc*64  + row
    const int t    = threadIdx.x;
    const int lane = t & 63, wv = t >> 6;
    const int wr   = wv >> 1, wc = wv & 1;
    const int q4   = lane >> 4, l16 = lane & 15;
    const int bn0  = blockIdx.x * 64;
    const int bm0  = blockIdx.y * 128;

    f32x4 acc[4][2] = {};

    const int cA0 = t, cA1 = t + 256;
    const short* gA0 = A  + (size_t)(bm0 + (cA0 & 127)) * K + (cA0 >> 7) * 8;
    const short* gA1 = A  + (size_t)(bm0 + (cA1 & 127)) * K + (cA1 >> 7) * 8;
    const short* gB0 = Bt + (size_t)(bn0 + (cA0 & 63))  * K + (cA0 >> 6) * 8;
    const short* lA0 = &As[(wv * 64) * 8];
    const short* lA1 = &As[(256 + wv * 64) * 8];
    const short* lB0 = &Bs[(wv * 64) * 8];

    const int kIters = K >> 5;
    for (int kt = 0; kt < kIters; ++kt) {
        __syncthreads();                       // prev iter's LDS reads done
        ld16_to_lds(gA0, lA0);
        ld16_to_lds(gA1, lA1);
        ld16_to_lds(gB0, lB0);
        gA0 += 32; gA1 += 32; gB0 += 32;
        __syncthreads();                       // staging (vmcnt) drained

        s16x8 aF[4], bF[2];
        #pragma unroll
        for (int i = 0; i < 4; ++i)
            aF[i] = *(const s16x8*)&As[(q4 * 128 + wr * 64 + i * 16 + l16) * 8];
        #pragma unroll
        for (int j = 0; j < 2; ++j)
            bF[j] = *(const s16x8*)&Bs[(q4 * 64 + wc * 32 + j * 16 + l16) * 8];
        #pragma unroll
        for (int i = 0; i < 4; ++i)
            #pragma unroll
            for (int j = 0; j < 2; ++j)
                acc[i][j] = __builtin_amdgcn_mfma_f32_16x16x32_bf16(
                    aF[i], bF[j], acc[i][j], 0, 0, 0);
    }

    // Epilogue: C/D layout col = lane&15, row = (lane>>4)*4 + reg
    #pragma unroll
    for (int j = 0; j < 2; ++j) {
        const int col = bn0 + wc * 32 + j * 16 + l16;
        const float bj = bias[col];
        #pragma unroll
        for (int i = 0; i < 4; ++i) {
            const int row0 = bm0 + wr * 64 + i * 16 + q4 * 4;
            #pragma unroll
            for (int r = 0; r < 4; ++r) {
                const float v = acc[i][j][r] + bj;
                if (F32OUT) ((float*)Cv)[(size_t)(row0 + r) * N + col] = v;
                else        ((short*)Cv)[(size_t)(row0 + r) * N + col] = f2bf(v);
            }
        }
    }
}

// ---------------------------------------------------------------------------
// Flash attention: Qp/Kp/Vp/Out are [B*S, D] bf16, head h = cols h*64..h*64+63.
// Block: 128 q-rows, 4 waves each owning 32 q-rows (no cross-wave reduction).
// KV tiles of 128. Online softmax in registers, P round-trips LDS (wave-
// private region, no barrier). V staged transposed with XOR swizzle.
// ---------------------------------------------------------------------------
__global__ __launch_bounds__(256)
void attn_fwd(const short* __restrict__ Qp, const short* __restrict__ Kp,
              const short* __restrict__ Vp, short* __restrict__ Out)
{
    constexpr int D = 1024, S = 2048;
    __shared__ short Ks[8 * 128 * 8];    // 16 KB: chunk (kc*128 + kvrow)
    __shared__ short Vt[16 * 64 * 8];    // 16 KB: elem kvc*512 + (d^kvc)*8 + kv&7
    __shared__ short Ps[4 * 16 * 32 * 8];// 32 KB: per-wave [kvc][m][8]

    const int t    = threadIdx.x;
    const int lane = t & 63, wv = t >> 6;
    const int q4   = lane >> 4, l16 = lane & 15;
    const int qt = blockIdx.x, h = blockIdx.y, b = blockIdx.z;
    const size_t rowB = (size_t)b * S;
    const int cb = h * 64;
    const int qrow0 = qt * 128 + wv * 32;

    // Q fragments straight from global: A-operand m = lane&15, k = quad*8+j
    s16x8 qF[2][2];
    #pragma unroll
    for (int i = 0; i < 2; ++i)
        #pragma unroll
        for (int tk = 0; tk < 2; ++tk)
            qF[i][tk] = *(const s16x8*)
                &Qp[(rowB + qrow0 + i * 16 + l16) * D + cb + tk * 32 + q4 * 8];

    f32x4 oacc[2][4] = {};
    float mrun[2][4], lrun[2][4];
    #pragma unroll
    for (int i = 0; i < 2; ++i)
        #pragma unroll
        for (int r = 0; r < 4; ++r) { mrun[i][r] = -INFINITY; lrun[i][r] = 0.f; }

    const float sc = 0.125f * 1.44269504088896f;  // log2(e)/sqrt(64)

    for (int kvt = 0; kvt < 16; ++kvt) {
        const int kv0 = kvt * 128;
        __syncthreads();                 // prev iter done with Ks/Vt
        #pragma unroll
        for (int half = 0; half < 4; ++half) {
            const int c = half * 256 + t;   // kc = c>>7, kvrow = c&127
            ld16_to_lds(&Kp[(rowB + kv0 + (c & 127)) * D + cb + (c >> 7) * 8],
                        &Ks[(half * 256 + wv * 64) * 8]);
        }
        #pragma unroll
        for (int half = 0; half < 4; ++half) {
            const int c = half * 256 + t;   // dc = c>>7, kv = c&127
            const int dc = c >> 7, kv = c & 127;
            const s16x8 vv = *(const s16x8*)&Vp[(rowB + kv0 + kv) * D + cb + dc * 8];
            const int kvc = kv >> 3, kvl = kv & 7;
            #pragma unroll
            for (int e = 0; e < 8; ++e)
                Vt[kvc * 512 + ((dc * 8 + e) ^ kvc) * 8 + kvl] = vv[e];
        }
        __syncthreads();                 // staging complete

        // scores: acc[i][j], rows m = i*16+q4*4+r, cols n = j*16+l16
        f32x4 acc[2][8] = {};
        #pragma unroll
        for (int tk = 0; tk < 2; ++tk) {
            #pragma unroll
            for (int j = 0; j < 8; ++j) {
                const s16x8 kF = *(const s16x8*)
                    &Ks[((tk * 4 + q4) * 128 + j * 16 + l16) * 8];
                acc[0][j] = __builtin_amdgcn_mfma_f32_16x16x32_bf16(
                    qF[0][tk], kF, acc[0][j], 0, 0, 0);
                acc[1][j] = __builtin_amdgcn_mfma_f32_16x16x32_bf16(
                    qF[1][tk], kF, acc[1][j], 0, 0, 0);
            }
        }

        // online softmax (per-row stats replicated across the 16-lane quad)
        #pragma unroll
        for (int i = 0; i < 2; ++i) {
            #pragma unroll
            for (int r = 0; r < 4; ++r) {
                float mx = acc[i][0][r];
                #pragma unroll
                for (int j = 1; j < 8; ++j) mx = fmaxf(mx, acc[i][j][r]);
                mx = fmaxf(mx, __shfl_xor(mx, 1));
                mx = fmaxf(mx, __shfl_xor(mx, 2));
                mx = fmaxf(mx, __shfl_xor(mx, 4));
                mx = fmaxf(mx, __shfl_xor(mx, 8));
                const float mold = mrun[i][r];
                const float mnew = fmaxf(mold, mx);
                const float alpha = exp2f((mold - mnew) * sc);
                mrun[i][r] = mnew;
                const int m = i * 16 + q4 * 4 + r;
                float rs = 0.f;
                #pragma unroll
                for (int j = 0; j < 8; ++j) {
                    const float p = exp2f((acc[i][j][r] - mnew) * sc);
                    rs += p;
                    // kv = j*16 + l16 -> kvc = j*2 + (l16>>3), e = l16&7
                    Ps[wv * 4096 + ((j * 2 + (l16 >> 3)) * 32 + m) * 8 + (l16 & 7)]
                        = f2bf(p);
                }
                rs += __shfl_xor(rs, 1);
                rs += __shfl_xor(rs, 2);
                rs += __shfl_xor(rs, 4);
                rs += __shfl_xor(rs, 8);
                lrun[i][r] = lrun[i][r] * alpha + rs;
                #pragma unroll
                for (int jd = 0; jd < 4; ++jd) oacc[i][jd][r] *= alpha;
            }
        }

        // PV: A-operand from wave-private Ps, B-operand from swizzled Vt
        #pragma unroll
        for (int tk = 0; tk < 4; ++tk) {
            const int kvc = tk * 4 + q4;
            s16x8 pF[2];
            pF[0] = *(const s16x8*)&Ps[wv * 4096 + (kvc * 32 + l16) * 8];
            pF[1] = *(const s16x8*)&Ps[wv * 4096 + (kvc * 32 + 16 + l16) * 8];
            #pragma unroll
            for (int jd = 0; jd < 4; ++jd) {
                const s16x8 vF = *(const s16x8*)
                    &Vt[kvc * 512 + ((jd * 16 + l16) ^ kvc) * 8];
                oacc[0][jd] = __builtin_amdgcn_mfma_f32_16x16x32_bf16(
                    pF[0], vF, oacc[0][jd], 0, 0, 0);
                oacc[1][jd] = __builtin_amdgcn_mfma_f32_16x16x32_bf16(
                    pF[1], vF, oacc[1][jd], 0, 0, 0);
            }
        }
    }

    // finalize: divide by l, store bf16
    #pragma unroll
    for (int i = 0; i < 2; ++i) {
        #pragma unroll
        for (int r = 0; r < 4; ++r) {
            const float inv = 1.0f / lrun[i][r];
            const size_t row = rowB + qrow0 + i * 16 + q4 * 4 + r;
            #pragma unroll
            for (int jd = 0; jd < 4; ++jd)
                Out[row * D + cb + jd * 16 + l16] = f2bf(oacc[i][jd][r] * inv);
        }
    }
}

// ---------------------------------------------------------------------------
// Fused fp32 -> bf16 cast of q,k,v (4M elems each) + Wq,Wk,Wv,Wo (1M each)
// into one contiguous 16M-element bf16 region at the start of d_ws.
// ---------------------------------------------------------------------------
__global__ __launch_bounds__(256)
void cast_all(const float* __restrict__ q, const float* __restrict__ k,
              const float* __restrict__ v, const float* __restrict__ wq,
              const float* __restrict__ wk, const float* __restrict__ wv,
              const float* __restrict__ wo, short* __restrict__ out)
{
    const size_t i = ((size_t)blockIdx.x * 256 + threadIdx.x) * 8;
    const float* src; size_t off;
    if      (i < 4194304)  { src = q;  off = i; }
    else if (i < 8388608)  { src = k;  off = i - 4194304; }
    else if (i < 12582912) { src = v;  off = i - 8388608; }
    else if (i < 13631488) { src = wq; off = i - 12582912; }
    else if (i < 14680064) { src = wk; off = i - 13631488; }
    else if (i < 15728640) { src = wv; off = i - 14680064; }
    else                   { src = wo; off = i - 15728640; }
    const float4 a = *(const float4*)(src + off);
    const float4 c = *(const float4*)(src + off + 4);
    s16x8 o;
    o[0] = f2bf(a.x); o[1] = f2bf(a.y); o[2] = f2bf(a.z); o[3] = f2bf(a.w);
    o[4] = f2bf(c.x); o[5] = f2bf(c.y); o[6] = f2bf(c.z); o[7] = f2bf(c.w);
    *(s16x8*)(out + i) = o;
}

extern "C" void kernel_launch(void* const* d_in, const int* in_sizes, int n_in,
                              void* d_out, int out_size, void* d_ws, size_t ws_size,
                              hipStream_t stream)
{
    const float* q  = (const float*)d_in[0];
    const float* k  = (const float*)d_in[1];
    const float* v  = (const float*)d_in[2];
    const float* Wq = (const float*)d_in[3];
    const float* bq = (const float*)d_in[4];
    const float* Wk = (const float*)d_in[5];
    const float* bk = (const float*)d_in[6];
    const float* Wv = (const float*)d_in[7];
    const float* bv = (const float*)d_in[8];
    const float* Wo = (const float*)d_in[9];
    const float* bo = (const float*)d_in[10];

    short* ws = (short*)d_ws;
    const size_t MEL = 1048576;
    short* Aq  = ws;               // queries bf16 [4096,1024]
    short* Ak  = ws + 4 * MEL;
    short* Av  = ws + 8 * MEL;
    short* Wqb = ws + 12 * MEL;    // weights bf16 [1024,1024]
    short* Wkb = ws + 13 * MEL;
    short* Wvb = ws + 14 * MEL;
    short* Wob = ws + 15 * MEL;
    short* Qp  = ws + 16 * MEL;    // projected Q/K/V bf16 [4096,1024]
    short* Kp  = ws + 20 * MEL;
    short* Vp  = ws + 24 * MEL;
    short* AO  = ws;               // attention out, reuses Aq region (dead by then)
    // total workspace: 28 MEL * 2 B = 56 MB

    cast_all<<<8192, 256, 0, stream>>>(q, k, v, Wq, Wk, Wv, Wo, ws);

    dim3 gg(16, 32);  // N/64, M/128
    gemm_bt<0><<<gg, 256, 0, stream>>>(Aq, Wqb, bq, Qp, 4096, 1024, 1024);
    gemm_bt<0><<<gg, 256, 0, stream>>>(Ak, Wkb, bk, Kp, 4096, 1024, 1024);
    gemm_bt<0><<<gg, 256, 0, stream>>>(Av, Wvb, bv, Vp, 4096, 1024, 1024);

    attn_fwd<<<dim3(16, 16, 2), 256, 0, stream>>>(Qp, Kp, Vp, AO);

    gemm_bt<1><<<gg, 256, 0, stream>>>(AO, Wob, bo, (float*)d_out, 4096, 1024, 1024);
}